// Round 9
// baseline (475.964 us; speedup 1.0000x reference)
//
#include <hip/hip_runtime.h>
#include <hip/hip_bf16.h>
#include <math.h>

typedef unsigned short u16;
typedef unsigned int   u32;
typedef __bf16  v8bf  __attribute__((ext_vector_type(8)));
typedef float   v4f   __attribute__((ext_vector_type(4)));

#define EPS_H 0.01f

typedef const __attribute__((address_space(1))) void* gas_t;
typedef __attribute__((address_space(3))) void* las_t;
#define GL2LDS(g,l) __builtin_amdgcn_global_load_lds((gas_t)(const void*)(g), (las_t)(void*)(l), 16, 0, 0)

#define VMW8()   asm volatile("s_waitcnt vmcnt(8)" ::: "memory")
#define VMW0()   asm volatile("s_waitcnt vmcnt(0)" ::: "memory")
#define BAR()    __builtin_amdgcn_s_barrier()
#define SCHED0() __builtin_amdgcn_sched_barrier(0)

__device__ __forceinline__ u16 f2bf(float f) {           // native RNE cvt
    __bf16 h = (__bf16)f;
    return *reinterpret_cast<u16*>(&h);
}
__device__ __forceinline__ float bfs(u16 v) { return __uint_as_float(((u32)v) << 16); }
__device__ __forceinline__ float selu_f(float x) {
    const float sc = 1.0507009873554805f, al = 1.6732632423543772f;
    return x > 0.f ? sc * x : sc * al * (__expf(x) - 1.0f);
}
__device__ __forceinline__ float gelu_f(float x) {
    return 0.5f * x * (1.f + erff(x * 0.7071067811865476f));
}
__device__ __forceinline__ float pe_val(int n, int j) {
    float t = 1000.0f * ((float)(j & ~1) * (1.0f / 512.0f)) + 0.01f;
    float a = (float)n / t;
    return (j & 1) ? cosf(a) : sinf(a);
}

// fragment read from a swizzled [128][32]-bf16 sub-tile (row stride 64B)
__device__ __forceinline__ v8bf lfrag(const u16* base, int row, int lane) {
    int g = (lane >> 4) ^ ((row >> 1) & 3);
    return *(const v8bf*)((const char*)base + row * 64 + g * 16);
}

// stage one 16-KB operand tile (two [128][32] sub-tiles), 4 waves, 4 GL2LDS/thread
__device__ __forceinline__ void stage2(const u16* g, size_t gstride, u16* lds, int wave, int lane) {
    const int l2 = lane >> 2;
    #pragma unroll
    for (int i = 0; i < 4; ++i) {
        const int ib  = wave * 4 + i;          // 0..15 chunks of 1024 B
        const int sub = ib >> 3;               // k-half
        const int rl  = (ib & 7) * 16 + l2;    // tile row
        const int gs  = (lane & 3) ^ ((rl >> 1) & 3);
        GL2LDS((const char*)(g + (size_t)rl * gstride + sub * 32) + gs * 16,
               (char*)lds + ib * 1024);
    }
}

#define COMPUTE_TILE(Abuf, Bbuf)                                                   \
    {                                                                              \
        const u16* A0 = &(Abuf)[0];    const u16* A1 = &(Abuf)[4096];              \
        const u16* B0 = &(Bbuf)[0];    const u16* B1 = &(Bbuf)[4096];              \
        v8bf b0[4], b1[4];                                                         \
        _Pragma("unroll")                                                          \
        for (int fc = 0; fc < 4; ++fc) {                                           \
            const int brow = wn * 64 + fc * 16 + (lane & 15);                      \
            b0[fc] = lfrag(B0, brow, lane);                                        \
            b1[fc] = lfrag(B1, brow, lane);                                        \
        }                                                                          \
        __builtin_amdgcn_s_setprio(1);                                             \
        _Pragma("unroll")                                                          \
        for (int fr = 0; fr < 4; ++fr) {                                           \
            const int arow = wm * 64 + fr * 16 + (lane & 15);                      \
            v8bf a0 = lfrag(A0, arow, lane);                                       \
            v8bf a1 = lfrag(A1, arow, lane);                                       \
            _Pragma("unroll")                                                      \
            for (int fc = 0; fc < 4; ++fc) {                                       \
                acc[fr][fc] = __builtin_amdgcn_mfma_f32_16x16x32_bf16(a0, b0[fc], acc[fr][fc], 0, 0, 0); \
                acc[fr][fc] = __builtin_amdgcn_mfma_f32_16x16x32_bf16(a1, b1[fc], acc[fr][fc], 0, 0, 0); \
            }                                                                      \
        }                                                                          \
        __builtin_amdgcn_s_setprio(0);                                             \
    }

// ---------------- K0: x fp32 -> bf16 (once)
__global__ __launch_bounds__(256)
void k_xbf(const float* __restrict__ x, u16* __restrict__ xbf)
{
    const size_t i = ((size_t)blockIdx.x * 256 + threadIdx.x) * 8;
    float4 a = *(const float4*)&x[i];
    float4 b = *(const float4*)&x[i + 4];
    ushort4 o0, o1;
    o0.x = f2bf(a.x); o0.y = f2bf(a.y); o0.z = f2bf(a.z); o0.w = f2bf(a.w);
    o1.x = f2bf(b.x); o1.y = f2bf(b.y); o1.z = f2bf(b.z); o1.w = f2bf(b.w);
    *(ushort4*)&xbf[i] = o0;
    *(ushort4*)&xbf[i + 4] = o1;
}

// ---------------- K1: 256x256 tile, 8 waves, BK=64, counted-vmcnt pipeline (16-seq chunk)
__global__ __launch_bounds__(512, 2)
void k1_qkv256(const u16* __restrict__ xbf, const u16* __restrict__ WT,
               const float* __restrict__ bias, u16* __restrict__ q,
               u16* __restrict__ kT, u16* __restrict__ vT)
{
    extern __shared__ u16 lds[];   // 128 KiB: A[c] @ c*16384, B[c] @ 32768 + c*16384
    const int tid = threadIdx.x, lane = tid & 63, wave = tid >> 6;
    const int orig = blockIdx.x + blockIdx.y * 6;          // grid (6, 64) = 384
    const int swz  = (orig & 7) * 48 + (orig >> 3);        // XCD-bijective (384 = 8*48)
    const int col0 = (swz % 6) * 256, row0 = (swz / 6) * 256;
    const int wm = wave >> 2, wn = wave & 3;               // 2M x 4N waves
    const u16* Ag = xbf + (size_t)row0 * 512;
    const u16* Bg = WT + (size_t)col0 * 512;
    v4f acc[8][4] = {};

    // stage one 32-KB 256x64 tile (4 sub-tiles [128][32]); 8 waves, 4 GL2LDS/thread
    auto stg = [&](const u16* g, u16* dst, int k0) {
        const int l2 = lane >> 2;
        #pragma unroll
        for (int i = 0; i < 4; ++i) {
            const int ib = wave * 4 + i;      // 0..31 chunks of 1024 B
            const int s  = ib >> 3;           // sub-tile: rowhalf = s>>1, khalf = s&1
            const int rl = (ib & 7) * 16 + l2;
            const int row = (s >> 1) * 128 + rl;
            const int gs = (lane & 3) ^ ((rl >> 1) & 3);
            GL2LDS((const char*)(g + (size_t)row * 512 + k0 + (s & 1) * 32) + gs * 16,
                   (char*)dst + ib * 1024);
        }
    };

    stg(Ag, lds, 0);          stg(Bg, lds + 32768, 0);      // 8 loads/thread
    stg(Ag, lds + 16384, 64); stg(Bg, lds + 49152, 64);     // +8 -> 16 outstanding

    for (int t = 0; t < 8; ++t) {
        const int c = t & 1;
        if (t < 7) VMW8(); else VMW0();        // keep next tile's loads in flight
        BAR(); SCHED0();
        {
            const u16* Ac = lds + c * 16384;
            const u16* Bc = lds + 32768 + c * 16384;
            v8bf bf[4][2];
            #pragma unroll
            for (int fn = 0; fn < 4; ++fn) {
                const int bsub = (wn >> 1) * 2;
                const int brow = (wn & 1) * 64 + fn * 16 + (lane & 15);
                bf[fn][0] = lfrag(Bc + (bsub + 0) * 4096, brow, lane);
                bf[fn][1] = lfrag(Bc + (bsub + 1) * 4096, brow, lane);
            }
            __builtin_amdgcn_s_setprio(1);
            #pragma unroll
            for (int fm = 0; fm < 8; ++fm) {
                const int asub = wm * 2;
                const int arow = fm * 16 + (lane & 15);
                v8bf a0 = lfrag(Ac + (asub + 0) * 4096, arow, lane);
                v8bf a1 = lfrag(Ac + (asub + 1) * 4096, arow, lane);
                #pragma unroll
                for (int fn = 0; fn < 4; ++fn) {
                    acc[fm][fn] = __builtin_amdgcn_mfma_f32_16x16x32_bf16(a0, bf[fn][0], acc[fm][fn], 0, 0, 0);
                    acc[fm][fn] = __builtin_amdgcn_mfma_f32_16x16x32_bf16(a1, bf[fn][1], acc[fm][fn], 0, 0, 0);
                }
            }
            __builtin_amdgcn_s_setprio(0);
        }
        BAR(); SCHED0();
        if (t + 2 < 8) {
            stg(Ag, lds + c * 16384, (t + 2) * 64);
            stg(Bg, lds + 32768 + c * 16384, (t + 2) * 64);
        }
    }

    const int region = col0 >> 9;   // 0:q 1:k 2:v (256-col strip never crosses a 512 boundary)
    #pragma unroll
    for (int fn = 0; fn < 4; ++fn) {
        const int c = col0 + wn * 64 + fn * 16 + (lane & 15);
        const float bc = bias[c];
        #pragma unroll
        for (int fm = 0; fm < 8; ++fm) {
            const int rb = row0 + wm * 128 + fm * 16 + ((lane >> 4) << 2);
            float v0 = selu_f(acc[fm][fn][0] + bc);
            float v1 = selu_f(acc[fm][fn][1] + bc);
            float v2 = selu_f(acc[fm][fn][2] + bc);
            float v3 = selu_f(acc[fm][fn][3] + bc);
            if (region == 0) {
                q[(size_t)(rb + 0) * 512 + c] = f2bf(v0);
                q[(size_t)(rb + 1) * 512 + c] = f2bf(v1);
                q[(size_t)(rb + 2) * 512 + c] = f2bf(v2);
                q[(size_t)(rb + 3) * 512 + c] = f2bf(v3);
            } else {
                ushort4 st; st.x = f2bf(v0); st.y = f2bf(v1); st.z = f2bf(v2); st.w = f2bf(v3);
                const int seq = rb >> 10, n = rb & 1023;    // chunk-local
                u16* dst = (region == 1) ? kT : vT;
                const int cc = c - ((region == 1) ? 512 : 1024);
                *(ushort4*)&dst[(size_t)seq * 524288 + (size_t)cc * 1024 + n] = st;
            }
        }
    }
}

// ---------------- K2: Mt[p][d] = (1/512) * sum_m K[m][d] V[m][p]   (per seq, chunk)
__global__ __launch_bounds__(256, 1)
void k2_ktv(const u16* __restrict__ kT, const u16* __restrict__ vT, u16* __restrict__ Mt)
{
    __shared__ u16 Als[2][8192];
    __shared__ u16 Bls[2][8192];
    const int tid = threadIdx.x, lane = tid & 63, wave = tid >> 6;
    const int d0 = blockIdx.x * 128, p0 = blockIdx.y * 128, seq = blockIdx.z;
    const u16* Ab = kT + (size_t)seq * 524288 + (size_t)d0 * 1024;
    const u16* Bb = vT + (size_t)seq * 524288 + (size_t)p0 * 1024;
    const int wm = wave >> 1, wn = wave & 1;
    v4f acc[4][4] = {};

    stage2(Ab,      1024, &Als[0][0], wave, lane);
    stage2(Bb,      1024, &Bls[0][0], wave, lane);
    stage2(Ab + 64, 1024, &Als[1][0], wave, lane);
    stage2(Bb + 64, 1024, &Bls[1][0], wave, lane);
    for (int t = 0; t < 16; ++t) {
        const int c = t & 1;
        if (t < 15) VMW8(); else VMW0();
        BAR(); SCHED0();
        COMPUTE_TILE(Als[c], Bls[c]);
        BAR(); SCHED0();
        if (t + 2 < 16) {
            const int m0 = (t + 2) * 64;
            stage2(Ab + m0, 1024, &Als[c][0], wave, lane);
            stage2(Bb + m0, 1024, &Bls[c][0], wave, lane);
        }
    }

    #pragma unroll
    for (int fn = 0; fn < 4; ++fn) {
        const int p = p0 + wn * 64 + fn * 16 + (lane & 15);
        #pragma unroll
        for (int fm = 0; fm < 4; ++fm) {
            const int d = d0 + wm * 64 + fm * 16 + ((lane >> 4) << 2);
            ushort4 st;
            st.x = f2bf(acc[fm][fn][0] * (1.f / 512.f));
            st.y = f2bf(acc[fm][fn][1] * (1.f / 512.f));
            st.z = f2bf(acc[fm][fn][2] * (1.f / 512.f));
            st.w = f2bf(acc[fm][fn][3] * (1.f / 512.f));
            *(ushort4*)&Mt[(size_t)seq * 262144 + (size_t)p * 512 + d] = st;
        }
    }
}

// ---------------- K3a: S[n][p] = sum_d q[n][d] * Mt[p][d]   (S bf16, chunk)
__global__ __launch_bounds__(256, 1)
void k3a_s(const u16* __restrict__ q, const u16* __restrict__ Mt, u16* __restrict__ S)
{
    __shared__ u16 Als[2][8192];
    __shared__ u16 Bls[2][8192];
    const int tid = threadIdx.x, lane = tid & 63, wave = tid >> 6;
    const int orig = blockIdx.x + blockIdx.y * 4;           // grid (4, 128) = 512
    const int swz  = (orig & 7) * 64 + (orig >> 3);
    const int p0 = (swz % 4) * 128, row0 = (swz / 4) * 128;
    const int seq = row0 >> 10;                              // chunk-local
    const u16* Ab = q + (size_t)row0 * 512;
    const u16* Bb = Mt + (size_t)seq * 262144 + (size_t)p0 * 512;
    const int wm = wave >> 1, wn = wave & 1;
    v4f acc[4][4] = {};

    stage2(Ab,      512, &Als[0][0], wave, lane);
    stage2(Bb,      512, &Bls[0][0], wave, lane);
    stage2(Ab + 64, 512, &Als[1][0], wave, lane);
    stage2(Bb + 64, 512, &Bls[1][0], wave, lane);
    for (int t = 0; t < 8; ++t) {
        const int c = t & 1;
        if (t < 7) VMW8(); else VMW0();
        BAR(); SCHED0();
        COMPUTE_TILE(Als[c], Bls[c]);
        BAR(); SCHED0();
        if (t + 2 < 8) {
            const int k0 = (t + 2) * 64;
            stage2(Ab + k0, 512, &Als[c][0], wave, lane);
            stage2(Bb + k0, 512, &Bls[c][0], wave, lane);
        }
    }

    #pragma unroll
    for (int fn = 0; fn < 4; ++fn) {
        const int c = p0 + wn * 64 + fn * 16 + (lane & 15);
        #pragma unroll
        for (int fm = 0; fm < 4; ++fm) {
            const int rb = row0 + wm * 64 + fm * 16 + ((lane >> 4) << 2);
            S[(size_t)(rb + 0) * 512 + c] = f2bf(acc[fm][fn][0]);
            S[(size_t)(rb + 1) * 512 + c] = f2bf(acc[fm][fn][1]);
            S[(size_t)(rb + 2) * 512 + c] = f2bf(acc[fm][fn][2]);
            S[(size_t)(rb + 3) * 512 + c] = f2bf(acc[fm][fn][3]);
        }
    }
}

// ---------------- K3b: in-place row softmax over 512 cols (one wave per row)
__global__ __launch_bounds__(256)
void k3b_sm(u16* __restrict__ S)
{
    const int row  = blockIdx.x * 4 + (threadIdx.x >> 6);
    const int lane = threadIdx.x & 63;
    u16* rp = S + (size_t)row * 512 + lane * 8;
    ushort4 u0 = *(const ushort4*)rp;
    ushort4 u1 = *(const ushort4*)(rp + 4);
    float f[8] = {bfs(u0.x), bfs(u0.y), bfs(u0.z), bfs(u0.w),
                  bfs(u1.x), bfs(u1.y), bfs(u1.z), bfs(u1.w)};
    float m = f[0];
    #pragma unroll
    for (int j = 1; j < 8; ++j) m = fmaxf(m, f[j]);
    #pragma unroll
    for (int off = 32; off > 0; off >>= 1) m = fmaxf(m, __shfl_xor(m, off));
    float s = 0.f;
    #pragma unroll
    for (int j = 0; j < 8; ++j) { f[j] = __expf(f[j] - m); s += f[j]; }
    #pragma unroll
    for (int off = 32; off > 0; off >>= 1) s += __shfl_xor(s, off);
    const float inv = 1.0f / s;
    ushort4 o0, o1;
    o0.x = f2bf(f[0] * inv); o0.y = f2bf(f[1] * inv);
    o0.z = f2bf(f[2] * inv); o0.w = f2bf(f[3] * inv);
    o1.x = f2bf(f[4] * inv); o1.y = f2bf(f[5] * inv);
    o1.z = f2bf(f[6] * inv); o1.w = f2bf(f[7] * inv);
    *(ushort4*)rp = o0;
    *(ushort4*)(rp + 4) = o1;
}

// ---------------- K3c: mode 0: out = gelu(att@WpT^T + bp)      (head 0)
//                       mode 1: out = gelu(...) + EPS*out + pe  (head 3, final)
__global__ __launch_bounds__(256, 1)
void k3c_proj(const u16* __restrict__ att, const u16* __restrict__ WpT,
              const float* __restrict__ bp, const float* __restrict__ pe,
              float* __restrict__ out, const int mode, const int rowbase)
{
    __shared__ u16 Als[2][8192];
    __shared__ u16 Bls[2][8192];
    const int tid = threadIdx.x, lane = tid & 63, wave = tid >> 6;
    const int orig = blockIdx.x + blockIdx.y * 4;           // grid (4, 128) = 512
    const int swz  = (orig & 7) * 64 + (orig >> 3);
    const int e0 = (swz % 4) * 128, row0 = (swz / 4) * 128;
    const u16* Ab = att + (size_t)row0 * 512;
    const u16* Bb = WpT + (size_t)e0 * 512;
    const int wm = wave >> 1, wn = wave & 1;
    v4f acc[4][4] = {};

    stage2(Ab,      512, &Als[0][0], wave, lane);
    stage2(Bb,      512, &Bls[0][0], wave, lane);
    stage2(Ab + 64, 512, &Als[1][0], wave, lane);
    stage2(Bb + 64, 512, &Bls[1][0], wave, lane);
    for (int t = 0; t < 8; ++t) {
        const int c = t & 1;
        if (t < 7) VMW8(); else VMW0();
        BAR(); SCHED0();
        COMPUTE_TILE(Als[c], Bls[c]);
        BAR(); SCHED0();
        if (t + 2 < 8) {
            const int k0 = (t + 2) * 64;
            stage2(Ab + k0, 512, &Als[c][0], wave, lane);
            stage2(Bb + k0, 512, &Bls[c][0], wave, lane);
        }
    }

    #pragma unroll
    for (int fn = 0; fn < 4; ++fn) {
        const int e = e0 + wn * 64 + fn * 16 + (lane & 15);
        const float be = bp[e];
        #pragma unroll
        for (int fm = 0; fm < 4; ++fm) {
            const int rb = row0 + wm * 64 + fm * 16 + ((lane >> 4) << 2);
            #pragma unroll
            for (int j = 0; j < 4; ++j) {
                const int r = rowbase + rb + j;
                const float g = gelu_f(acc[fm][fn][j] + be);
                const size_t o = (size_t)r * 512 + e;
                if (mode == 0) out[o] = g;
                else           out[o] = g + EPS_H * out[o] + pe[(r & 1023) * 512 + e];
            }
        }
    }
}

// ---------------- prep: fp32 [rows][cols] -> bf16 transposed [cols][rows]
__global__ __launch_bounds__(256)
void k_tr(const float* __restrict__ src, u16* __restrict__ dst, int rows, int cols)
{
    __shared__ float t[32][33];
    const int tid = threadIdx.x;
    const int c0 = blockIdx.x * 32, r0 = blockIdx.y * 32;
    #pragma unroll
    for (int i = 0; i < 4; ++i) {
        int idx = tid + i * 256;
        int rr = idx >> 5, cc = idx & 31;
        t[rr][cc] = src[(size_t)(r0 + rr) * cols + c0 + cc];
    }
    __syncthreads();
    #pragma unroll
    for (int i = 0; i < 4; ++i) {
        int idx = tid + i * 256;
        int rr = idx >> 5, cc = idx & 31;
        dst[(size_t)(c0 + rr) * rows + r0 + cc] = f2bf(t[cc][rr]);
    }
}

__global__ __launch_bounds__(256)
void k_pe(float* __restrict__ pe)
{
    int idx = blockIdx.x * 256 + threadIdx.x;
    pe[idx] = pe_val(idx >> 9, idx & 511);
}

extern "C" void kernel_launch(void* const* d_in, const int* in_sizes, int n_in,
                              void* d_out, int out_size, void* d_ws, size_t ws_size,
                              hipStream_t stream)
{
    const float* x    = (const float*)d_in[0];
    const float* Wqkv = (const float*)d_in[1];
    const float* bqkv = (const float*)d_in[2];
    const float* Wp   = (const float*)d_in[3];
    const float* bp   = (const float*)d_in[4];
    float* out = (float*)d_out;

    char* ws = (char*)d_ws;                       // ~98.5 MiB total (R7-proven layout)
    u16*   xbf = (u16*)(ws);                      // 32 MiB  [32768][512] bf16
    u16*   q   = (u16*)(ws + 33554432);           // 16 MiB  [16384][512]      (chunk)
    u16*   kT  = (u16*)(ws + 50331648);           // 16 MiB  [16][512][1024]   (chunk; S alias)
    u16*   vT  = (u16*)(ws + 67108864);           // 16 MiB  [16][512][1024]   (chunk)
    u16*   Mt  = (u16*)(ws + 83886080);           //  8 MiB  [16][512][512]    (chunk)
    u16*   WqT = (u16*)(ws + 92274688);           //  3 MiB  [2][1536][512]
    u16*   WpT = (u16*)(ws + 95420416);           //  1 MiB  [2][512][512]
    float* pe  = (float*)(ws + 96468992);         //  2 MiB  [1024][512]
    u16*   S   = kT;                              // S/att alias (kT dead after K2)

    // allow 128 KiB dynamic LDS for the 256^2 kernel (not a stream op; graph-safe)
    (void)hipFuncSetAttribute((const void*)k1_qkv256,
                              hipFuncAttributeMaxDynamicSharedMemorySize, 131072);

    k_xbf<<<8192, 256, 0, stream>>>(x, xbf);
    k_pe<<<2048, 256, 0, stream>>>(pe);
    for (int hh = 0; hh < 2; ++hh) {
        const int h = hh ? 3 : 0;   // heads 1,2 provably do not affect the output
        k_tr<<<dim3(48, 16), 256, 0, stream>>>(Wqkv + (size_t)h * 786432, WqT + (size_t)hh * 786432, 512, 1536);
        k_tr<<<dim3(16, 16), 256, 0, stream>>>(Wp   + (size_t)h * 262144, WpT + (size_t)hh * 262144, 512, 512);
    }
    for (int p = 0; p < 2; ++p) {
        const int h = p ? 3 : 0;
        for (int ck = 0; ck < 2; ++ck) {
            const u16* xc = xbf + (size_t)ck * 16384 * 512;
            k1_qkv256<<<dim3(6, 64), 512, 131072, stream>>>(xc, WqT + (size_t)p * 786432,
                                                            bqkv + (size_t)h * 1536, q, kT, vT);
            k2_ktv<<<dim3(4, 4, 16), 256, 0, stream>>>(kT, vT, Mt);
            k3a_s<<<dim3(4, 128), 256, 0, stream>>>(q, Mt, S);
            k3b_sm<<<4096, 256, 0, stream>>>(S);
            k3c_proj<<<dim3(4, 128), 256, 0, stream>>>(S, WpT + (size_t)p * 262144,
                                                       bp + (size_t)h * 512, pe, out, p, ck * 16384);
        }
    }
}

// Round 10
// 436.929 us; speedup vs baseline: 1.0893x; 1.0893x over previous
//
#include <hip/hip_runtime.h>
#include <hip/hip_bf16.h>
#include <math.h>

typedef unsigned short u16;
typedef unsigned int   u32;
typedef __bf16  v8bf  __attribute__((ext_vector_type(8)));
typedef float   v4f   __attribute__((ext_vector_type(4)));

#define EPS_H 0.01f

typedef const __attribute__((address_space(1))) void* gas_t;
typedef __attribute__((address_space(3))) void* las_t;
#define GL2LDS(g,l) __builtin_amdgcn_global_load_lds((gas_t)(const void*)(g), (las_t)(void*)(l), 16, 0, 0)

#define VMW8()   asm volatile("s_waitcnt vmcnt(8)" ::: "memory")
#define VMW0()   asm volatile("s_waitcnt vmcnt(0)" ::: "memory")
#define BAR()    __builtin_amdgcn_s_barrier()
#define SCHED0() __builtin_amdgcn_sched_barrier(0)

__device__ __forceinline__ u16 f2bf(float f) {           // native RNE cvt
    __bf16 h = (__bf16)f;
    return *reinterpret_cast<u16*>(&h);
}
__device__ __forceinline__ float bfs(u16 v) { return __uint_as_float(((u32)v) << 16); }
__device__ __forceinline__ float selu_f(float x) {
    const float sc = 1.0507009873554805f, al = 1.6732632423543772f;
    return x > 0.f ? sc * x : sc * al * (__expf(x) - 1.0f);
}
__device__ __forceinline__ float gelu_f(float x) {
    return 0.5f * x * (1.f + erff(x * 0.7071067811865476f));
}
__device__ __forceinline__ float pe_val(int n, int j) {
    float t = 1000.0f * ((float)(j & ~1) * (1.0f / 512.0f)) + 0.01f;
    float a = (float)n / t;
    return (j & 1) ? cosf(a) : sinf(a);
}

// fragment read from a swizzled [128][32]-bf16 sub-tile (row stride 64B)
__device__ __forceinline__ v8bf lfrag(const u16* base, int row, int lane) {
    int g = (lane >> 4) ^ ((row >> 1) & 3);
    return *(const v8bf*)((const char*)base + row * 64 + g * 16);
}

// stage one 16-KB operand tile (two [128][32] sub-tiles), 4 waves, 4 GL2LDS/thread
__device__ __forceinline__ void stage2(const u16* g, size_t gstride, u16* lds, int wave, int lane) {
    const int l2 = lane >> 2;
    #pragma unroll
    for (int i = 0; i < 4; ++i) {
        const int ib  = wave * 4 + i;          // 0..15 chunks of 1024 B
        const int sub = ib >> 3;               // k-half
        const int rl  = (ib & 7) * 16 + l2;    // tile row
        const int gs  = (lane & 3) ^ ((rl >> 1) & 3);
        GL2LDS((const char*)(g + (size_t)rl * gstride + sub * 32) + gs * 16,
               (char*)lds + ib * 1024);
    }
}

#define COMPUTE_TILE(Abuf, Bbuf)                                                   \
    {                                                                              \
        const u16* A0 = &(Abuf)[0];    const u16* A1 = &(Abuf)[4096];              \
        const u16* B0 = &(Bbuf)[0];    const u16* B1 = &(Bbuf)[4096];              \
        v8bf b0[4], b1[4];                                                         \
        _Pragma("unroll")                                                          \
        for (int fc = 0; fc < 4; ++fc) {                                           \
            const int brow = wn * 64 + fc * 16 + (lane & 15);                      \
            b0[fc] = lfrag(B0, brow, lane);                                        \
            b1[fc] = lfrag(B1, brow, lane);                                        \
        }                                                                          \
        __builtin_amdgcn_s_setprio(1);                                             \
        _Pragma("unroll")                                                          \
        for (int fr = 0; fr < 4; ++fr) {                                           \
            const int arow = wm * 64 + fr * 16 + (lane & 15);                      \
            v8bf a0 = lfrag(A0, arow, lane);                                       \
            v8bf a1 = lfrag(A1, arow, lane);                                       \
            _Pragma("unroll")                                                      \
            for (int fc = 0; fc < 4; ++fc) {                                       \
                acc[fr][fc] = __builtin_amdgcn_mfma_f32_16x16x32_bf16(a0, b0[fc], acc[fr][fc], 0, 0, 0); \
                acc[fr][fc] = __builtin_amdgcn_mfma_f32_16x16x32_bf16(a1, b1[fc], acc[fr][fc], 0, 0, 0); \
            }                                                                      \
        }                                                                          \
        __builtin_amdgcn_s_setprio(0);                                             \
    }

// ---------------- K_prep: xbf cvt + pe table + 4 weight transposes, one launch
// sections: [0,8192) xbf | [8192,10240) pe | [10240,11776) WqT | [11776,12288) WpT
__global__ __launch_bounds__(256)
void k_prep(const float* __restrict__ x, u16* __restrict__ xbf, float* __restrict__ pe,
            const float* __restrict__ Wqkv, u16* __restrict__ WqT,
            const float* __restrict__ Wp, u16* __restrict__ WpT)
{
    __shared__ float t[32][33];
    const int b = blockIdx.x, tid = threadIdx.x;
    if (b < 8192) {                                   // x fp32 -> bf16
        const size_t i = ((size_t)b * 256 + tid) * 8;
        float4 a = *(const float4*)&x[i];
        float4 c = *(const float4*)&x[i + 4];
        ushort4 o0, o1;
        o0.x = f2bf(a.x); o0.y = f2bf(a.y); o0.z = f2bf(a.z); o0.w = f2bf(a.w);
        o1.x = f2bf(c.x); o1.y = f2bf(c.y); o1.z = f2bf(c.z); o1.w = f2bf(c.w);
        *(ushort4*)&xbf[i] = o0;
        *(ushort4*)&xbf[i + 4] = o1;
        return;
    }
    if (b < 10240) {                                  // pe table
        int idx = (b - 8192) * 256 + tid;
        pe[idx] = pe_val(idx >> 9, idx & 511);
        return;
    }
    const float* src; u16* dst; int rows, cols, bx, by;
    if (b < 11776) {                                  // Wqkv[h] transpose (512x1536)
        int l = b - 10240, hh = l / 768, rem = l % 768;
        bx = rem % 48; by = rem / 48;
        src = Wqkv + (size_t)(hh ? 3 : 0) * 786432; dst = WqT + (size_t)hh * 786432;
        rows = 512; cols = 1536;
    } else {                                          // Wp[h] transpose (512x512)
        int l = b - 11776, hh = l / 256, rem = l % 256;
        bx = rem % 16; by = rem / 16;
        src = Wp + (size_t)(hh ? 3 : 0) * 262144; dst = WpT + (size_t)hh * 262144;
        rows = 512; cols = 512;
    }
    const int c0 = bx * 32, r0 = by * 32;
    #pragma unroll
    for (int i = 0; i < 4; ++i) {
        int idx = tid + i * 256;
        int rr = idx >> 5, cc = idx & 31;
        t[rr][cc] = src[(size_t)(r0 + rr) * cols + c0 + cc];
    }
    __syncthreads();
    #pragma unroll
    for (int i = 0; i < 4; ++i) {
        int idx = tid + i * 256;
        int rr = idx >> 5, cc = idx & 31;
        dst[(size_t)(c0 + rr) * rows + r0 + cc] = f2bf(t[cc][rr]);
    }
}

// ---------------- K1: qkv = selu(x @ W + b); q row-major, k/v transposed (16-seq chunk)
//                     128^2 tile, 4 waves, BK=64, counted-vmcnt pipeline
__global__ __launch_bounds__(256, 1)
void k1_qkv(const u16* __restrict__ xbf, const u16* __restrict__ WT,
            const float* __restrict__ bias, u16* __restrict__ q,
            u16* __restrict__ kT, u16* __restrict__ vT)
{
    __shared__ u16 Als[2][8192];
    __shared__ u16 Bls[2][8192];
    const int tid = threadIdx.x, lane = tid & 63, wave = tid >> 6;
    const int orig = blockIdx.x + blockIdx.y * 12;          // grid (12, 128) = 1536
    const int swz  = (orig & 7) * 192 + (orig >> 3);        // XCD-bijective
    const int col0 = (swz % 12) * 128, row0 = (swz / 12) * 128;
    const int wm = wave >> 1, wn = wave & 1;
    const u16* Ab = xbf + (size_t)row0 * 512;
    const u16* Bb = WT + (size_t)col0 * 512;
    v4f acc[4][4] = {};

    stage2(Ab,      512, &Als[0][0], wave, lane);
    stage2(Bb,      512, &Bls[0][0], wave, lane);
    stage2(Ab + 64, 512, &Als[1][0], wave, lane);
    stage2(Bb + 64, 512, &Bls[1][0], wave, lane);
    for (int t = 0; t < 8; ++t) {
        const int c = t & 1;
        if (t < 7) VMW8(); else VMW0();
        BAR(); SCHED0();
        COMPUTE_TILE(Als[c], Bls[c]);
        BAR(); SCHED0();
        if (t + 2 < 8) {
            const int k0 = (t + 2) * 64;
            stage2(Ab + k0, 512, &Als[c][0], wave, lane);
            stage2(Bb + k0, 512, &Bls[c][0], wave, lane);
        }
    }

    const int region = col0 >> 9;   // 0:q 1:k 2:v (block-uniform)
    #pragma unroll
    for (int fn = 0; fn < 4; ++fn) {
        const int c = col0 + wn * 64 + fn * 16 + (lane & 15);
        const float bc = bias[c];
        #pragma unroll
        for (int fm = 0; fm < 4; ++fm) {
            const int rb = row0 + wm * 64 + fm * 16 + ((lane >> 4) << 2);
            float v0 = selu_f(acc[fm][fn][0] + bc);
            float v1 = selu_f(acc[fm][fn][1] + bc);
            float v2 = selu_f(acc[fm][fn][2] + bc);
            float v3 = selu_f(acc[fm][fn][3] + bc);
            if (region == 0) {
                q[(size_t)(rb + 0) * 512 + c] = f2bf(v0);
                q[(size_t)(rb + 1) * 512 + c] = f2bf(v1);
                q[(size_t)(rb + 2) * 512 + c] = f2bf(v2);
                q[(size_t)(rb + 3) * 512 + c] = f2bf(v3);
            } else {
                ushort4 st; st.x = f2bf(v0); st.y = f2bf(v1); st.z = f2bf(v2); st.w = f2bf(v3);
                const int seq = rb >> 10, n = rb & 1023;    // chunk-local
                u16* dst = (region == 1) ? kT : vT;
                const int cc = c - ((region == 1) ? 512 : 1024);
                *(ushort4*)&dst[(size_t)seq * 524288 + (size_t)cc * 1024 + n] = st;
            }
        }
    }
}

// ---------------- K2: Mt[p][d] = (1/512) * sum_m K[m][d] V[m][p]   (per seq, chunk)
__global__ __launch_bounds__(256, 1)
void k2_ktv(const u16* __restrict__ kT, const u16* __restrict__ vT, u16* __restrict__ Mt)
{
    __shared__ u16 Als[2][8192];
    __shared__ u16 Bls[2][8192];
    const int tid = threadIdx.x, lane = tid & 63, wave = tid >> 6;
    const int d0 = blockIdx.x * 128, p0 = blockIdx.y * 128, seq = blockIdx.z;
    const u16* Ab = kT + (size_t)seq * 524288 + (size_t)d0 * 1024;
    const u16* Bb = vT + (size_t)seq * 524288 + (size_t)p0 * 1024;
    const int wm = wave >> 1, wn = wave & 1;
    v4f acc[4][4] = {};

    stage2(Ab,      1024, &Als[0][0], wave, lane);
    stage2(Bb,      1024, &Bls[0][0], wave, lane);
    stage2(Ab + 64, 1024, &Als[1][0], wave, lane);
    stage2(Bb + 64, 1024, &Bls[1][0], wave, lane);
    for (int t = 0; t < 16; ++t) {
        const int c = t & 1;
        if (t < 15) VMW8(); else VMW0();
        BAR(); SCHED0();
        COMPUTE_TILE(Als[c], Bls[c]);
        BAR(); SCHED0();
        if (t + 2 < 16) {
            const int m0 = (t + 2) * 64;
            stage2(Ab + m0, 1024, &Als[c][0], wave, lane);
            stage2(Bb + m0, 1024, &Bls[c][0], wave, lane);
        }
    }

    #pragma unroll
    for (int fn = 0; fn < 4; ++fn) {
        const int p = p0 + wn * 64 + fn * 16 + (lane & 15);
        #pragma unroll
        for (int fm = 0; fm < 4; ++fm) {
            const int d = d0 + wm * 64 + fm * 16 + ((lane >> 4) << 2);
            ushort4 st;
            st.x = f2bf(acc[fm][fn][0] * (1.f / 512.f));
            st.y = f2bf(acc[fm][fn][1] * (1.f / 512.f));
            st.z = f2bf(acc[fm][fn][2] * (1.f / 512.f));
            st.w = f2bf(acc[fm][fn][3] * (1.f / 512.f));
            *(ushort4*)&Mt[(size_t)seq * 262144 + (size_t)p * 512 + d] = st;
        }
    }
}

// ---------------- K3a: S[n][p] = sum_d q[n][d] * Mt[p][d]   (S bf16, chunk)
__global__ __launch_bounds__(256, 1)
void k3a_s(const u16* __restrict__ q, const u16* __restrict__ Mt, u16* __restrict__ S)
{
    __shared__ u16 Als[2][8192];
    __shared__ u16 Bls[2][8192];
    const int tid = threadIdx.x, lane = tid & 63, wave = tid >> 6;
    const int orig = blockIdx.x + blockIdx.y * 4;           // grid (4, 128) = 512
    const int swz  = (orig & 7) * 64 + (orig >> 3);
    const int p0 = (swz % 4) * 128, row0 = (swz / 4) * 128;
    const int seq = row0 >> 10;                              // chunk-local
    const u16* Ab = q + (size_t)row0 * 512;
    const u16* Bb = Mt + (size_t)seq * 262144 + (size_t)p0 * 512;
    const int wm = wave >> 1, wn = wave & 1;
    v4f acc[4][4] = {};

    stage2(Ab,      512, &Als[0][0], wave, lane);
    stage2(Bb,      512, &Bls[0][0], wave, lane);
    stage2(Ab + 64, 512, &Als[1][0], wave, lane);
    stage2(Bb + 64, 512, &Bls[1][0], wave, lane);
    for (int t = 0; t < 8; ++t) {
        const int c = t & 1;
        if (t < 7) VMW8(); else VMW0();
        BAR(); SCHED0();
        COMPUTE_TILE(Als[c], Bls[c]);
        BAR(); SCHED0();
        if (t + 2 < 8) {
            const int k0 = (t + 2) * 64;
            stage2(Ab + k0, 512, &Als[c][0], wave, lane);
            stage2(Bb + k0, 512, &Bls[c][0], wave, lane);
        }
    }

    #pragma unroll
    for (int fn = 0; fn < 4; ++fn) {
        const int c = p0 + wn * 64 + fn * 16 + (lane & 15);
        #pragma unroll
        for (int fm = 0; fm < 4; ++fm) {
            const int rb = row0 + wm * 64 + fm * 16 + ((lane >> 4) << 2);
            S[(size_t)(rb + 0) * 512 + c] = f2bf(acc[fm][fn][0]);
            S[(size_t)(rb + 1) * 512 + c] = f2bf(acc[fm][fn][1]);
            S[(size_t)(rb + 2) * 512 + c] = f2bf(acc[fm][fn][2]);
            S[(size_t)(rb + 3) * 512 + c] = f2bf(acc[fm][fn][3]);
        }
    }
}

// ---------------- K3b: in-place row softmax over 512 cols (one wave per row)
__global__ __launch_bounds__(256)
void k3b_sm(u16* __restrict__ S)
{
    const int row  = blockIdx.x * 4 + (threadIdx.x >> 6);
    const int lane = threadIdx.x & 63;
    u16* rp = S + (size_t)row * 512 + lane * 8;
    ushort4 u0 = *(const ushort4*)rp;
    ushort4 u1 = *(const ushort4*)(rp + 4);
    float f[8] = {bfs(u0.x), bfs(u0.y), bfs(u0.z), bfs(u0.w),
                  bfs(u1.x), bfs(u1.y), bfs(u1.z), bfs(u1.w)};
    float m = f[0];
    #pragma unroll
    for (int j = 1; j < 8; ++j) m = fmaxf(m, f[j]);
    #pragma unroll
    for (int off = 32; off > 0; off >>= 1) m = fmaxf(m, __shfl_xor(m, off));
    float s = 0.f;
    #pragma unroll
    for (int j = 0; j < 8; ++j) { f[j] = __expf(f[j] - m); s += f[j]; }
    #pragma unroll
    for (int off = 32; off > 0; off >>= 1) s += __shfl_xor(s, off);
    const float inv = 1.0f / s;
    ushort4 o0, o1;
    o0.x = f2bf(f[0] * inv); o0.y = f2bf(f[1] * inv);
    o0.z = f2bf(f[2] * inv); o0.w = f2bf(f[3] * inv);
    o1.x = f2bf(f[4] * inv); o1.y = f2bf(f[5] * inv);
    o1.z = f2bf(f[6] * inv); o1.w = f2bf(f[7] * inv);
    *(ushort4*)rp = o0;
    *(ushort4*)(rp + 4) = o1;
}

// ---------------- K3c: mode 0: out = gelu(att@WpT^T + bp)      (head 0)
//                       mode 1: out = gelu(...) + EPS*out + pe  (head 3, final)
__global__ __launch_bounds__(256, 1)
void k3c_proj(const u16* __restrict__ att, const u16* __restrict__ WpT,
              const float* __restrict__ bp, const float* __restrict__ pe,
              float* __restrict__ out, const int mode, const int rowbase)
{
    __shared__ u16 Als[2][8192];
    __shared__ u16 Bls[2][8192];
    const int tid = threadIdx.x, lane = tid & 63, wave = tid >> 6;
    const int orig = blockIdx.x + blockIdx.y * 4;           // grid (4, 128) = 512
    const int swz  = (orig & 7) * 64 + (orig >> 3);
    const int e0 = (swz % 4) * 128, row0 = (swz / 4) * 128;
    const u16* Ab = att + (size_t)row0 * 512;
    const u16* Bb = WpT + (size_t)e0 * 512;
    const int wm = wave >> 1, wn = wave & 1;
    v4f acc[4][4] = {};

    stage2(Ab,      512, &Als[0][0], wave, lane);
    stage2(Bb,      512, &Bls[0][0], wave, lane);
    stage2(Ab + 64, 512, &Als[1][0], wave, lane);
    stage2(Bb + 64, 512, &Bls[1][0], wave, lane);
    for (int t = 0; t < 8; ++t) {
        const int c = t & 1;
        if (t < 7) VMW8(); else VMW0();
        BAR(); SCHED0();
        COMPUTE_TILE(Als[c], Bls[c]);
        BAR(); SCHED0();
        if (t + 2 < 8) {
            const int k0 = (t + 2) * 64;
            stage2(Ab + k0, 512, &Als[c][0], wave, lane);
            stage2(Bb + k0, 512, &Bls[c][0], wave, lane);
        }
    }

    #pragma unroll
    for (int fn = 0; fn < 4; ++fn) {
        const int e = e0 + wn * 64 + fn * 16 + (lane & 15);
        const float be = bp[e];
        #pragma unroll
        for (int fm = 0; fm < 4; ++fm) {
            const int rb = row0 + wm * 64 + fm * 16 + ((lane >> 4) << 2);
            #pragma unroll
            for (int j = 0; j < 4; ++j) {
                const int r = rowbase + rb + j;
                const float g = gelu_f(acc[fm][fn][j] + be);
                const size_t o = (size_t)r * 512 + e;
                if (mode == 0) out[o] = g;
                else           out[o] = g + EPS_H * out[o] + pe[(r & 1023) * 512 + e];
            }
        }
    }
}

extern "C" void kernel_launch(void* const* d_in, const int* in_sizes, int n_in,
                              void* d_out, int out_size, void* d_ws, size_t ws_size,
                              hipStream_t stream)
{
    const float* x    = (const float*)d_in[0];
    const float* Wqkv = (const float*)d_in[1];
    const float* bqkv = (const float*)d_in[2];
    const float* Wp   = (const float*)d_in[3];
    const float* bp   = (const float*)d_in[4];
    float* out = (float*)d_out;

    char* ws = (char*)d_ws;                       // ~98.5 MiB total (R7-proven layout)
    u16*   xbf = (u16*)(ws);                      // 32 MiB  [32768][512] bf16
    u16*   q   = (u16*)(ws + 33554432);           // 16 MiB  [16384][512]      (chunk)
    u16*   kT  = (u16*)(ws + 50331648);           // 16 MiB  [16][512][1024]   (chunk; S alias)
    u16*   vT  = (u16*)(ws + 67108864);           // 16 MiB  [16][512][1024]   (chunk)
    u16*   Mt  = (u16*)(ws + 83886080);           //  8 MiB  [16][512][512]    (chunk)
    u16*   WqT = (u16*)(ws + 92274688);           //  3 MiB  [2][1536][512]
    u16*   WpT = (u16*)(ws + 95420416);           //  1 MiB  [2][512][512]
    float* pe  = (float*)(ws + 96468992);         //  2 MiB  [1024][512]
    u16*   S   = kT;                              // S/att alias (kT dead after K2)

    k_prep<<<12288, 256, 0, stream>>>(x, xbf, pe, Wqkv, WqT, Wp, WpT);
    for (int p = 0; p < 2; ++p) {
        const int h = p ? 3 : 0;   // heads 1,2 provably do not affect the output
        for (int ck = 0; ck < 2; ++ck) {
            const u16* xc = xbf + (size_t)ck * 16384 * 512;
            k1_qkv<<<dim3(12, 128), 256, 0, stream>>>(xc, WqT + (size_t)p * 786432,
                                                      bqkv + (size_t)h * 1536, q, kT, vT);
            k2_ktv<<<dim3(4, 4, 16), 256, 0, stream>>>(kT, vT, Mt);
            k3a_s<<<dim3(4, 128), 256, 0, stream>>>(q, Mt, S);
            k3b_sm<<<4096, 256, 0, stream>>>(S);
            k3c_proj<<<dim3(4, 128), 256, 0, stream>>>(S, WpT + (size_t)p * 262144,
                                                       bp + (size_t)h * 512, pe, out, p, ck * 16384);
        }
    }
}